// Round 4
// baseline (94.208 us; speedup 1.0000x reference)
//
#include <hip/hip_runtime.h>

#define BB 4
#define NN 4096
#define GG 1024
#define CC 32
#define NSIG 4
#define PVALS 132          // 128 acc + 4 dens per (b,g)

// sigma = {0.01, 0.05, 0.1, 0.2} -> k = -0.5/sigma^2 = {-5000, -200, -50, -12.5}
// w(0.1)=w(0.2)^4, w(0.05)=w(0.1)^4 (repeated squaring); exp2 only for 0.2, 0.01.
#define C3 (-18.033688011112042f)   // -12.5/ln2  (sigma=0.2)
#define C0 (-7213.4752044448170f)   // -5000/ln2  (sigma=0.01)

typedef __attribute__((ext_vector_type(8))) short bf16x8;
typedef __attribute__((ext_vector_type(4))) float f32x4;

union frag_u { unsigned u[4]; bf16x8 v; };

// Pair-pack two f32 -> packed bf16x2. If lo/hi were ever swapped it stays
// correct: A-frags and B-frags pack the k(=n) dimension with the same
// function, and sum_n a_n b_n is invariant under consistent pair swaps.
#if __has_builtin(__builtin_amdgcn_cvt_pk_bf16_f32)
__device__ __forceinline__ unsigned pack_bf16(float lo, float hi) {
    return __builtin_bit_cast(unsigned, __builtin_amdgcn_cvt_pk_bf16_f32(lo, hi));
}
#else
__device__ __forceinline__ unsigned pack_bf16(float lo, float hi) {
    unsigned a = __float_as_uint(lo) + 0x8000u;
    unsigned b = __float_as_uint(hi) + 0x8000u;
    return __builtin_amdgcn_perm(b, a, 0x07060302u);
}
#endif

// ---- prep: feat*mask -> bf16 in MFMA-B-frag order; mask -> linear bf16 ----
// frag layout: element (b, n, c) -> row R = b*256 + (n/16 rounded to even) + c/16
// (1024 B rows), lane = ((n%32)/8)*16 + c%16, word = (n%8)/2, half = n%2.
__global__ __launch_bounds__(256) void gsc_prep_kernel(
    const float* __restrict__ pf, const float* __restrict__ pm,
    unsigned* __restrict__ fragw, unsigned* __restrict__ maskw)
{
    const int gid  = blockIdx.x * 256 + threadIdx.x;
    const int c    = gid & 31;
    const int rest = gid >> 5;
    const int np   = rest & (NN / 2 - 1);
    const int b    = rest >> 11;
    const int nl   = np * 2;
    const size_t ng = (size_t)b * NN + nl;
    const float m0 = pm[ng], m1 = pm[ng + 1];
    const float f0 = pf[ng * CC + c] * m0;
    const float f1 = pf[(ng + 1) * CC + c] * m1;
    const int ks = nl >> 5, qq = (nl >> 3) & 3, j = nl & 7, h = c >> 4;
    fragw[(((size_t)b * (NN / 32) + ks) * 2 + h) * 256 +
          (((qq << 4) | (c & 15)) << 2) + (j >> 1)] = pack_bf16(f0, f1);
    if (c == 0) maskw[ng >> 1] = pack_bf16(m0, m1);
}

// ---- main: ONE wave per block, 16 g's per wave, no LDS, no barriers.
// B-frags load straight from ws (already lane-ordered) via global dwordx4;
// the compiler software-pipelines these with fine-grained vmcnt.
__global__ __launch_bounds__(64) void gsc_mfma_kernel(
    const float* __restrict__ px, const unsigned* __restrict__ fragw,
    const unsigned* __restrict__ maskw, const float* __restrict__ gx,
    float* __restrict__ partial, float* __restrict__ out0,
    float* __restrict__ out1, int nchunk, int direct)
{
    const int l  = threadIdx.x;
    const int q  = l >> 4;
    const int cl = l & 15;

    int bid = blockIdx.x;
    const int nc = bid % nchunk; bid /= nchunk;
    const int gt = bid % (GG / 16);
    const int b  = bid / (GG / 16);
    const int gbase = gt * 16;

    // A-operand layout: A[m = lane&15][k = quad*8 + j] -> lane's g = gbase+cl
    const float gxv = gx[gbase + cl];

    f32x4 acc[NSIG][2];
    f32x4 dacc[NSIG];
#pragma unroll
    for (int s = 0; s < NSIG; ++s) {
        acc[s][0] = (f32x4){0.f, 0.f, 0.f, 0.f};
        acc[s][1] = (f32x4){0.f, 0.f, 0.f, 0.f};
        dacc[s]   = (f32x4){0.f, 0.f, 0.f, 0.f};
    }

    const int chunk   = NN / nchunk;
    const int n_begin = nc * chunk;
    const int KS      = chunk / 32;

    // lane-resolved base pointers (1024 B frag row = 64 bf16x8 slots)
    const bf16x8* fB = (const bf16x8*)fragw +
                       ((size_t)b * 256 + (n_begin >> 4)) * 64 + l;
    const float*  xB = px + (size_t)b * NN + n_begin + q * 8;
    const bf16x8* mB = (const bf16x8*)maskw +
                       (((size_t)b * NN + n_begin) >> 4) + q;

#pragma unroll 4
    for (int ks = 0; ks < KS; ++ks) {
        const bf16x8 bf0 = fB[ks * 128];        // row 2*ks,   this lane
        const bf16x8 bf1 = fB[ks * 128 + 64];   // row 2*ks+1, this lane
        const bf16x8 amv = mB[ks * 4];          // 8 bf16 mask, quad's points
        const float4 xa  = *(const float4*)(xB + ks * 32);
        const float4 xb4 = *(const float4*)(xB + ks * 32 + 4);

        float tt[8];
        float d;
        d = xa.x  - gxv; tt[0] = d * d;
        d = xa.y  - gxv; tt[1] = d * d;
        d = xa.z  - gxv; tt[2] = d * d;
        d = xa.w  - gxv; tt[3] = d * d;
        d = xb4.x - gxv; tt[4] = d * d;
        d = xb4.y - gxv; tt[5] = d * d;
        d = xb4.z - gxv; tt[6] = d * d;
        d = xb4.w - gxv; tt[7] = d * d;

        frag_u a0, a1, a2, a3;
#pragma unroll
        for (int j = 0; j < 8; j += 2) {
            const float w3a = __builtin_amdgcn_exp2f(tt[j]     * C3);
            const float w3b = __builtin_amdgcn_exp2f(tt[j + 1] * C3);
            float s;
            s = w3a * w3a; const float w2a = s * s;   // ^4 -> sigma 0.1
            s = w3b * w3b; const float w2b = s * s;
            s = w2a * w2a; const float w1a = s * s;   // ^4 -> sigma 0.05
            s = w2b * w2b; const float w1b = s * s;
            const float w0a = __builtin_amdgcn_exp2f(tt[j]     * C0);
            const float w0b = __builtin_amdgcn_exp2f(tt[j + 1] * C0);
            a3.u[j >> 1] = pack_bf16(w3a, w3b);
            a2.u[j >> 1] = pack_bf16(w2a, w2b);
            a1.u[j >> 1] = pack_bf16(w1a, w1b);
            a0.u[j >> 1] = pack_bf16(w0a, w0b);
        }

        acc[0][0] = __builtin_amdgcn_mfma_f32_16x16x32_bf16(a0.v, bf0, acc[0][0], 0, 0, 0);
        acc[0][1] = __builtin_amdgcn_mfma_f32_16x16x32_bf16(a0.v, bf1, acc[0][1], 0, 0, 0);
        dacc[0]   = __builtin_amdgcn_mfma_f32_16x16x32_bf16(a0.v, amv, dacc[0], 0, 0, 0);
        acc[1][0] = __builtin_amdgcn_mfma_f32_16x16x32_bf16(a1.v, bf0, acc[1][0], 0, 0, 0);
        acc[1][1] = __builtin_amdgcn_mfma_f32_16x16x32_bf16(a1.v, bf1, acc[1][1], 0, 0, 0);
        dacc[1]   = __builtin_amdgcn_mfma_f32_16x16x32_bf16(a1.v, amv, dacc[1], 0, 0, 0);
        acc[2][0] = __builtin_amdgcn_mfma_f32_16x16x32_bf16(a2.v, bf0, acc[2][0], 0, 0, 0);
        acc[2][1] = __builtin_amdgcn_mfma_f32_16x16x32_bf16(a2.v, bf1, acc[2][1], 0, 0, 0);
        dacc[2]   = __builtin_amdgcn_mfma_f32_16x16x32_bf16(a2.v, amv, dacc[2], 0, 0, 0);
        acc[3][0] = __builtin_amdgcn_mfma_f32_16x16x32_bf16(a3.v, bf0, acc[3][0], 0, 0, 0);
        acc[3][1] = __builtin_amdgcn_mfma_f32_16x16x32_bf16(a3.v, bf1, acc[3][1], 0, 0, 0);
        dacc[3]   = __builtin_amdgcn_mfma_f32_16x16x32_bf16(a3.v, amv, dacc[3], 0, 0, 0);
    }

    // ---- epilogue. C/D layout: col(c) = lane&15 (+16h), row(g) = quad*4+reg
    if (!direct) {
        float* p = partial + ((size_t)nc * BB * GG + (size_t)b * GG + gbase) * PVALS;
#pragma unroll
        for (int s = 0; s < NSIG; ++s)
#pragma unroll
            for (int h = 0; h < 2; ++h)
#pragma unroll
                for (int r = 0; r < 4; ++r)
                    p[(q * 4 + r) * PVALS + s * 32 + h * 16 + cl] = acc[s][h][r];
        if (cl == 0) {
#pragma unroll
            for (int s = 0; s < NSIG; ++s)
#pragma unroll
                for (int r = 0; r < 4; ++r)
                    p[(q * 4 + r) * PVALS + 128 + s] = dacc[s][r];
        }
    } else {
        float* o0 = out0 + ((size_t)b * GG + gbase) * (NSIG * CC);
        float* o1 = out1 + ((size_t)b * GG + gbase) * NSIG;
#pragma unroll
        for (int s = 0; s < NSIG; ++s)
#pragma unroll
            for (int r = 0; r < 4; ++r) {
                const float dd = dacc[s][r];
                const float inv = 1.0f / fmaxf(dd, 1e-6f);
#pragma unroll
                for (int h = 0; h < 2; ++h)
                    o0[(q * 4 + r) * (NSIG * CC) + s * CC + h * 16 + cl] = acc[s][h][r] * inv;
                if (cl == 0) o1[(q * 4 + r) * NSIG + s] = dd;
            }
    }
}

// ---- reduce: sum partials over n-chunks, divide, write final outputs ----
__global__ __launch_bounds__(128) void gsc_reduce_kernel(
    const float* __restrict__ partial, float* __restrict__ out0,
    float* __restrict__ out1, int nchunk)
{
    const size_t bg = blockIdx.x;
    const int v = threadIdx.x;   // 0..127 -> (s = v>>5, c = v&31)
    const int s = v >> 5;
    float num = 0.0f, dn = 0.0f;
    for (int nc = 0; nc < nchunk; ++nc) {
        const float* p = partial + ((size_t)nc * BB * GG + bg) * PVALS;
        num += p[v];
        dn  += p[128 + s];
    }
    out0[bg * 128 + v] = num / fmaxf(dn, 1e-6f);
    if (v < NSIG) {
        float d = 0.0f;
        for (int nc = 0; nc < nchunk; ++nc)
            d += partial[((size_t)nc * BB * GG + bg) * PVALS + 128 + v];
        out1[bg * NSIG + v] = d;
    }
}

extern "C" void kernel_launch(void* const* d_in, const int* in_sizes, int n_in,
                              void* d_out, int out_size, void* d_ws, size_t ws_size,
                              hipStream_t stream) {
    const float* px = (const float*)d_in[0];  // [B,N]
    const float* pf = (const float*)d_in[1];  // [B,N,C]
    const float* pm = (const float*)d_in[2];  // [B,N]
    const float* gx = (const float*)d_in[3];  // [G]
    float* out0 = (float*)d_out;                          // [B,G,4*C]
    float* out1 = out0 + (size_t)BB * GG * NSIG * CC;     // [B,G,4]

    const size_t fragWords = (size_t)BB * 256 * 256;   // 1 MB
    const size_t maskWords = (size_t)BB * NN / 2;      // 32 KB
    unsigned* fragw = (unsigned*)d_ws;
    unsigned* maskw = fragw + fragWords;
    float* partial  = (float*)(maskw + maskWords);
    const size_t used  = (fragWords + maskWords) * 4;
    const size_t avail = ws_size > used ? ws_size - used : 0;
    const size_t per   = (size_t)BB * GG * PVALS * sizeof(float);

    int nchunk = 1, direct = 1;
    if (8 * per <= avail)      { nchunk = 8; direct = 0; }
    else if (4 * per <= avail) { nchunk = 4; direct = 0; }
    else if (2 * per <= avail) { nchunk = 2; direct = 0; }
    else if (per <= avail)     { nchunk = 1; direct = 0; }

    gsc_prep_kernel<<<dim3(BB * (NN / 2) * CC / 256), dim3(256), 0, stream>>>(
        pf, pm, fragw, maskw);
    gsc_mfma_kernel<<<dim3(BB * (GG / 16) * nchunk), dim3(64), 0, stream>>>(
        px, fragw, maskw, gx, partial, out0, out1, nchunk, direct);
    if (!direct)
        gsc_reduce_kernel<<<dim3(BB * GG), dim3(128), 0, stream>>>(
            partial, out0, out1, nchunk);
}

// Round 7
// 93.885 us; speedup vs baseline: 1.0034x; 1.0034x over previous
//
#include <hip/hip_runtime.h>

#define BB 4
#define NN 4096
#define GG 1024
#define CC 32
#define NSIG 4
#define PVALS 132          // 128 acc + 4 dens per (b,g)

// sigma = {0.01, 0.05, 0.1, 0.2} -> k = -0.5/sigma^2 = {-5000, -200, -50, -12.5}
// w(0.1)=w(0.2)^4, w(0.05)=w(0.1)^4 (repeated squaring); exp2 only for 0.2, 0.01.
#define C3 (-18.033688011112042f)   // -12.5/ln2  (sigma=0.2)
#define C0 (-7213.4752044448170f)   // -5000/ln2  (sigma=0.01)

typedef __attribute__((ext_vector_type(8))) short bf16x8;
typedef __attribute__((ext_vector_type(4))) float f32x4;

union frag_u { unsigned u[4]; bf16x8 v; };

#if __has_builtin(__builtin_amdgcn_cvt_pk_bf16_f32)
__device__ __forceinline__ unsigned pack_bf16(float lo, float hi) {
    return __builtin_bit_cast(unsigned, __builtin_amdgcn_cvt_pk_bf16_f32(lo, hi));
}
#else
__device__ __forceinline__ unsigned pack_bf16(float lo, float hi) {
    unsigned a = __float_as_uint(lo) + 0x8000u;
    unsigned b = __float_as_uint(hi) + 0x8000u;
    return __builtin_amdgcn_perm(b, a, 0x07060302u);
}
#endif

// ---- prep: feat*mask -> bf16 in MFMA-B-frag order; mask -> linear bf16 ----
// frag layout: element (b, n, c) -> row R = b*256 + 2*(n/32) + c/16 (1024 B
// rows), lane = ((n%32)/8)*16 + c%16, word = (n%8)/2, half = n%2.
__global__ __launch_bounds__(256) void gsc_prep_kernel(
    const float* __restrict__ pf, const float* __restrict__ pm,
    unsigned* __restrict__ fragw, unsigned* __restrict__ maskw)
{
    const int gid  = blockIdx.x * 256 + threadIdx.x;
    const int c    = gid & 31;
    const int rest = gid >> 5;
    const int np   = rest & (NN / 2 - 1);
    const int b    = rest >> 11;
    const int nl   = np * 2;
    const size_t ng = (size_t)b * NN + nl;
    const float m0 = pm[ng], m1 = pm[ng + 1];
    const float f0 = pf[ng * CC + c] * m0;
    const float f1 = pf[(ng + 1) * CC + c] * m1;
    const int ks = nl >> 5, qq = (nl >> 3) & 3, j = nl & 7, h = c >> 4;
    fragw[(((size_t)b * (NN / 32) + ks) * 2 + h) * 256 +
          (((qq << 4) | (c & 15)) << 2) + (j >> 1)] = pack_bf16(f0, f1);
    if (c == 0) maskw[ng >> 1] = pack_bf16(m0, m1);
}

// ---- main: 128-thr blocks = 2 independent waves (two g-tiles), no LDS, no
// barriers. nchunk=16 gives 4096 waves (16/CU). Explicit next-iteration
// register prefetch overlaps global loads with compute without the VGPR
// pressure of a big unroll.
__global__ __launch_bounds__(128) void gsc_mfma_kernel(
    const float* __restrict__ px, const unsigned* __restrict__ fragw,
    const unsigned* __restrict__ maskw, const float* __restrict__ gx,
    float* __restrict__ partial, float* __restrict__ out0,
    float* __restrict__ out1, int nchunk, int direct)
{
    const int w  = threadIdx.x >> 6;
    const int l  = threadIdx.x & 63;
    const int q  = l >> 4;
    const int cl = l & 15;

    int bid = blockIdx.x;
    const int nc = bid % nchunk; bid /= nchunk;
    const int gp = bid % (GG / 32);
    const int b  = bid / (GG / 32);
    const int gbase = (gp * 2 + w) * 16;

    // A-operand layout: A[m = lane&15][k = quad*8 + j] -> lane's g = gbase+cl
    const float gxv = gx[gbase + cl];

    f32x4 acc[NSIG][2];
    f32x4 dacc[NSIG];
#pragma unroll
    for (int s = 0; s < NSIG; ++s) {
        acc[s][0] = (f32x4){0.f, 0.f, 0.f, 0.f};
        acc[s][1] = (f32x4){0.f, 0.f, 0.f, 0.f};
        dacc[s]   = (f32x4){0.f, 0.f, 0.f, 0.f};
    }

    const int chunk   = NN / nchunk;
    const int n_begin = nc * chunk;
    const int KS      = chunk / 32;

    // lane-resolved base pointers (1024 B frag row = 64 bf16x8 slots)
    const bf16x8* fB = (const bf16x8*)fragw +
                       ((size_t)b * 256 + (n_begin >> 4)) * 64 + l;
    const float*  xB = px + (size_t)b * NN + n_begin + q * 8;
    const bf16x8* mB = (const bf16x8*)maskw +
                       (((size_t)b * NN + n_begin) >> 4) + q;

    // prefetch iteration 0
    bf16x8 bf0 = fB[0];
    bf16x8 bf1 = fB[64];
    bf16x8 amv = mB[0];
    float4 xa  = *(const float4*)(xB);
    float4 xb4 = *(const float4*)(xB + 4);

#pragma unroll 1
    for (int ks = 0; ks < KS; ++ks) {
        // issue next iteration's loads before computing this one
        const int kn = (ks + 1 < KS) ? (ks + 1) : ks;
        const bf16x8 nbf0 = fB[kn * 128];
        const bf16x8 nbf1 = fB[kn * 128 + 64];
        const bf16x8 namv = mB[kn * 4];
        const float4 nxa  = *(const float4*)(xB + kn * 32);
        const float4 nxb4 = *(const float4*)(xB + kn * 32 + 4);

        float tt[8];
        float d;
        d = xa.x  - gxv; tt[0] = d * d;
        d = xa.y  - gxv; tt[1] = d * d;
        d = xa.z  - gxv; tt[2] = d * d;
        d = xa.w  - gxv; tt[3] = d * d;
        d = xb4.x - gxv; tt[4] = d * d;
        d = xb4.y - gxv; tt[5] = d * d;
        d = xb4.z - gxv; tt[6] = d * d;
        d = xb4.w - gxv; tt[7] = d * d;

        frag_u a0, a1, a2, a3;
#pragma unroll
        for (int j = 0; j < 8; j += 2) {
            const float w3a = __builtin_amdgcn_exp2f(tt[j]     * C3);
            const float w3b = __builtin_amdgcn_exp2f(tt[j + 1] * C3);
            float s;
            s = w3a * w3a; const float w2a = s * s;   // ^4 -> sigma 0.1
            s = w3b * w3b; const float w2b = s * s;
            s = w2a * w2a; const float w1a = s * s;   // ^4 -> sigma 0.05
            s = w2b * w2b; const float w1b = s * s;
            const float w0a = __builtin_amdgcn_exp2f(tt[j]     * C0);
            const float w0b = __builtin_amdgcn_exp2f(tt[j + 1] * C0);
            a3.u[j >> 1] = pack_bf16(w3a, w3b);
            a2.u[j >> 1] = pack_bf16(w2a, w2b);
            a1.u[j >> 1] = pack_bf16(w1a, w1b);
            a0.u[j >> 1] = pack_bf16(w0a, w0b);
        }

        acc[0][0] = __builtin_amdgcn_mfma_f32_16x16x32_bf16(a0.v, bf0, acc[0][0], 0, 0, 0);
        acc[0][1] = __builtin_amdgcn_mfma_f32_16x16x32_bf16(a0.v, bf1, acc[0][1], 0, 0, 0);
        dacc[0]   = __builtin_amdgcn_mfma_f32_16x16x32_bf16(a0.v, amv, dacc[0], 0, 0, 0);
        acc[1][0] = __builtin_amdgcn_mfma_f32_16x16x32_bf16(a1.v, bf0, acc[1][0], 0, 0, 0);
        acc[1][1] = __builtin_amdgcn_mfma_f32_16x16x32_bf16(a1.v, bf1, acc[1][1], 0, 0, 0);
        dacc[1]   = __builtin_amdgcn_mfma_f32_16x16x32_bf16(a1.v, amv, dacc[1], 0, 0, 0);
        acc[2][0] = __builtin_amdgcn_mfma_f32_16x16x32_bf16(a2.v, bf0, acc[2][0], 0, 0, 0);
        acc[2][1] = __builtin_amdgcn_mfma_f32_16x16x32_bf16(a2.v, bf1, acc[2][1], 0, 0, 0);
        dacc[2]   = __builtin_amdgcn_mfma_f32_16x16x32_bf16(a2.v, amv, dacc[2], 0, 0, 0);
        acc[3][0] = __builtin_amdgcn_mfma_f32_16x16x32_bf16(a3.v, bf0, acc[3][0], 0, 0, 0);
        acc[3][1] = __builtin_amdgcn_mfma_f32_16x16x32_bf16(a3.v, bf1, acc[3][1], 0, 0, 0);
        dacc[3]   = __builtin_amdgcn_mfma_f32_16x16x32_bf16(a3.v, amv, dacc[3], 0, 0, 0);

        bf0 = nbf0; bf1 = nbf1; amv = namv; xa = nxa; xb4 = nxb4;
    }

    // ---- epilogue. C/D layout: col(c) = lane&15 (+16h), row(g) = quad*4+reg
    if (!direct) {
        float* p = partial + ((size_t)nc * BB * GG + (size_t)b * GG + gbase) * PVALS;
#pragma unroll
        for (int s = 0; s < NSIG; ++s)
#pragma unroll
            for (int h = 0; h < 2; ++h)
#pragma unroll
                for (int r = 0; r < 4; ++r)
                    p[(q * 4 + r) * PVALS + s * 32 + h * 16 + cl] = acc[s][h][r];
        if (cl == 0) {
#pragma unroll
            for (int s = 0; s < NSIG; ++s)
#pragma unroll
                for (int r = 0; r < 4; ++r)
                    p[(q * 4 + r) * PVALS + 128 + s] = dacc[s][r];
        }
    } else {
        float* o0 = out0 + ((size_t)b * GG + gbase) * (NSIG * CC);
        float* o1 = out1 + ((size_t)b * GG + gbase) * NSIG;
#pragma unroll
        for (int s = 0; s < NSIG; ++s)
#pragma unroll
            for (int r = 0; r < 4; ++r) {
                const float dd = dacc[s][r];
                const float inv = 1.0f / fmaxf(dd, 1e-6f);
#pragma unroll
                for (int h = 0; h < 2; ++h)
                    o0[(q * 4 + r) * (NSIG * CC) + s * CC + h * 16 + cl] = acc[s][h][r] * inv;
                if (cl == 0) o1[(q * 4 + r) * NSIG + s] = dd;
            }
    }
}

// ---- reduce: sum partials over n-chunks, divide, write final outputs ----
__global__ __launch_bounds__(128) void gsc_reduce_kernel(
    const float* __restrict__ partial, float* __restrict__ out0,
    float* __restrict__ out1, int nchunk)
{
    const size_t bg = blockIdx.x;
    const int v = threadIdx.x;   // 0..127 -> (s = v>>5, c = v&31)
    const int s = v >> 5;
    float num = 0.0f, dn = 0.0f;
    for (int nc = 0; nc < nchunk; ++nc) {
        const float* p = partial + ((size_t)nc * BB * GG + bg) * PVALS;
        num += p[v];
        dn  += p[128 + s];
    }
    out0[bg * 128 + v] = num / fmaxf(dn, 1e-6f);
    if (v < NSIG) {
        float d = 0.0f;
        for (int nc = 0; nc < nchunk; ++nc)
            d += partial[((size_t)nc * BB * GG + bg) * PVALS + 128 + v];
        out1[bg * NSIG + v] = d;
    }
}

extern "C" void kernel_launch(void* const* d_in, const int* in_sizes, int n_in,
                              void* d_out, int out_size, void* d_ws, size_t ws_size,
                              hipStream_t stream) {
    const float* px = (const float*)d_in[0];  // [B,N]
    const float* pf = (const float*)d_in[1];  // [B,N,C]
    const float* pm = (const float*)d_in[2];  // [B,N]
    const float* gx = (const float*)d_in[3];  // [G]
    float* out0 = (float*)d_out;                          // [B,G,4*C]
    float* out1 = out0 + (size_t)BB * GG * NSIG * CC;     // [B,G,4]

    const size_t fragWords = (size_t)BB * 256 * 256;   // 1 MB
    const size_t maskWords = (size_t)BB * NN / 2;      // 32 KB
    unsigned* fragw = (unsigned*)d_ws;
    unsigned* maskw = fragw + fragWords;
    float* partial  = (float*)(maskw + maskWords);
    const size_t used  = (fragWords + maskWords) * 4;
    const size_t avail = ws_size > used ? ws_size - used : 0;
    const size_t per   = (size_t)BB * GG * PVALS * sizeof(float);

    int nchunk = 1, direct = 1;
    if (16 * per <= avail)      { nchunk = 16; direct = 0; }
    else if (8 * per <= avail)  { nchunk = 8;  direct = 0; }
    else if (4 * per <= avail)  { nchunk = 4;  direct = 0; }
    else if (2 * per <= avail)  { nchunk = 2;  direct = 0; }
    else if (per <= avail)      { nchunk = 1;  direct = 0; }

    gsc_prep_kernel<<<dim3(BB * (NN / 2) * CC / 256), dim3(256), 0, stream>>>(
        pf, pm, fragw, maskw);
    gsc_mfma_kernel<<<dim3(BB * (GG / 32) * nchunk), dim3(128), 0, stream>>>(
        px, fragw, maskw, gx, partial, out0, out1, nchunk, direct);
    if (!direct)
        gsc_reduce_kernel<<<dim3(BB * GG), dim3(128), 0, stream>>>(
            partial, out0, out1, nchunk);
}